// Round 4
// baseline (1738.986 us; speedup 1.0000x reference)
//
#include <hip/hip_runtime.h>
#include <math.h>

#define NN 100000
#define EE 1600000
#define GG 1000
#define NBUK 391          // ceil(NN/256) buckets, 256 nodes each
#define BCAP 4608         // per-bucket record capacity (mean 4092, sigma 64 -> +8 sigma)
#define EPB 4096          // edges per binning block
#define NBINBLK ((EE + EPB - 1) / EPB)   // 391

// ---- counts[g] += 1 per node ------------------------------------------------
__global__ void k_counts(const int* __restrict__ batch, float* __restrict__ counts, int n) {
    int i = blockIdx.x * blockDim.x + threadIdx.x;
    if (i < n) atomicAdd(&counts[batch[i]], 1.0f);
}

// ---- bin edges by dst>>8 into fixed-capacity bucket arrays ------------------
// record: x = (local_dst<<24) | src (src<2^17), y = float bits of weight
__global__ void k_bin(const int* __restrict__ src, const int* __restrict__ dst,
                      const float* __restrict__ ew, int* __restrict__ cursor,
                      uint2* __restrict__ ep, int E) {
    __shared__ int hist[NBUK];
    __shared__ int gbase[NBUK];
    int tid = threadIdx.x;
    for (int i = tid; i < NBUK; i += 256) hist[i] = 0;
    __syncthreads();

    int base = blockIdx.x * EPB;
    int b[16], rank[16];
    unsigned x[16], w[16];
#pragma unroll
    for (int u = 0; u < 16; u++) {
        int e = base + u * 256 + tid;
        if (e < E) {
            int d = dst[e];
            b[u] = d >> 8;
            x[u] = ((unsigned)(d & 255) << 24) | (unsigned)src[e];
            w[u] = __float_as_uint(ew[e]);
            rank[u] = atomicAdd(&hist[b[u]], 1);
        } else b[u] = -1;
    }
    __syncthreads();
    for (int i = tid; i < NBUK; i += 256) {
        int h = hist[i];
        gbase[i] = h ? atomicAdd(&cursor[i], h) : 0;
    }
    __syncthreads();
#pragma unroll
    for (int u = 0; u < 16; u++) {
        if (b[u] >= 0) {
            int pos = b[u] * BCAP + gbase[b[u]] + rank[u];
            ep[pos] = make_uint2(x[u], w[u]);
        }
    }
}

// ---- out[r][c] = sum_k in'[r][k] * W[k][c] ---------------------------------
template<bool ACT>
__global__ void k_gemm64(const float* __restrict__ in, const float* __restrict__ W,
                         const float* __restrict__ bPrev, const float* __restrict__ counts,
                         const int* __restrict__ batch, float* __restrict__ out, int n) {
    __shared__ float Ws[64 * 64];
    __shared__ float Rs[4][64];
    int tid = threadIdx.x;
    const float4* W4 = (const float4*)W;
    float4* Ws4 = (float4*)Ws;
#pragma unroll
    for (int i = 0; i < 4; i++) Ws4[tid + 256 * i] = W4[tid + 256 * i];

    int r = tid >> 6;
    int c = tid & 63;
    int row = blockIdx.x * 4 + r;
    float v = 0.f;
    if (row < n) {
        v = in[(size_t)row * 64 + c];
        if (ACT) {
            float cp = counts[batch[row]];
            v = v / cp + bPrev[c];
            v = 1.f / (1.f + __expf(-v));
        }
    }
    Rs[r][c] = v;
    __syncthreads();

    float acc = 0.f;
#pragma unroll
    for (int k = 0; k < 64; k++)
        acc = fmaf(Rs[r][k], Ws[k * 64 + c], acc);
    if (row < n) out[(size_t)row * 64 + c] = acc;
}

// ---- bucketed 64-ch aggregation into LDS, no global atomics -----------------
// MODE 0: agg[node][lane] = sum  -> coalesced write
// MODE 1: y[node] = sum_lane sigmoid(acc/cpn + b2[lane]) * W3[lane]
template<int MODE>
__global__ __launch_bounds__(512)
void k_agg(const float* __restrict__ t, const uint2* __restrict__ ep,
           const int* __restrict__ cnts, float* __restrict__ outp,
           const float* __restrict__ b2, const float* __restrict__ W3,
           const float* __restrict__ counts, const int* __restrict__ batch) {
    __shared__ float acc[256 * 64];   // 64 KB
    int tid = threadIdx.x;
    int wid = tid >> 6, lane = tid & 63;
    int bk = blockIdx.x;
    int ebase = bk * BCAP;
    int cnt = cnts[bk];

    float4* acc4 = (float4*)acc;
    for (int i = tid; i < 256 * 16; i += 512) acc4[i] = make_float4(0.f, 0.f, 0.f, 0.f);
    __syncthreads();

    for (int e0 = wid * 4; e0 < cnt; e0 += 8 * 4) {
        int eb = __builtin_amdgcn_readfirstlane(e0);
        int nu = cnt - eb; if (nu > 4) nu = 4;
        float v[4], wgt[4]; int ld[4];
#pragma unroll
        for (int u = 0; u < 4; u++) {
            if (u < nu) {
                uint2 r = ep[ebase + eb + u];
                int s = (int)(r.x & 0xFFFFFF);
                ld[u] = (int)(r.x >> 24);
                wgt[u] = __uint_as_float(r.y);
                v[u] = t[(size_t)s * 64 + lane];
            }
        }
#pragma unroll
        for (int u = 0; u < 4; u++)
            if (u < nu) atomicAdd(&acc[ld[u] * 64 + lane], wgt[u] * v[u]);
    }
    __syncthreads();

    int valid = NN - bk * 256; if (valid > 256) valid = 256;
    if (MODE == 0) {
        for (int i = tid; i < valid * 16; i += 512)
            ((float4*)outp)[(size_t)bk * 4096 + i] = acc4[i];
    } else {
        float b2l = b2[lane], w3l = W3[lane];
        for (int i = wid; i < valid; i += 8) {
            int node = bk * 256 + i;
            float cp = counts[batch[node]];
            float v = acc[i * 64 + lane] / cp + b2l;
            v = 1.f / (1.f + __expf(-v));
            v *= w3l;
#pragma unroll
            for (int off = 32; off > 0; off >>= 1) v += __shfl_down(v, off, 64);
            if (lane == 0) outp[node] = v;
        }
    }
}

// ---- layer-3 scalar aggregation + graph-mean pool ---------------------------
__global__ void k_y3pool(const float* __restrict__ y, const uint2* __restrict__ ep,
                         const int* __restrict__ cnts, const float* __restrict__ b3,
                         const float* __restrict__ counts, const int* __restrict__ batch,
                         float* __restrict__ out) {
    __shared__ float a1[256];
    int tid = threadIdx.x;
    int bk = blockIdx.x;
    a1[tid] = 0.f;
    __syncthreads();
    int cnt = cnts[bk];
    int ebase = bk * BCAP;
    for (int e = tid; e < cnt; e += 256) {
        uint2 r = ep[ebase + e];
        float yv = y[r.x & 0xFFFFFF];
        atomicAdd(&a1[r.x >> 24], __uint_as_float(r.y) * yv);
    }
    __syncthreads();
    int node = bk * 256 + tid;
    if (node < NN) {
        int g = batch[node];
        float c = counts[g];
        atomicAdd(&out[g], (a1[tid] / c + b3[0]) / c);
    }
}

extern "C" void kernel_launch(void* const* d_in, const int* in_sizes, int n_in,
                              void* d_out, int out_size, void* d_ws, size_t ws_size,
                              hipStream_t stream) {
    const float* x     = (const float*)d_in[0];
    const int*   ei    = (const int*)d_in[1];
    const int*   src   = ei;
    const int*   dst   = ei + EE;
    const float* ew    = (const float*)d_in[2];
    const int*   batch = (const int*)d_in[3];
    const float* W1    = (const float*)d_in[4];
    const float* b1    = (const float*)d_in[5];
    const float* W2    = (const float*)d_in[6];
    const float* b2    = (const float*)d_in[7];
    const float* W3    = (const float*)d_in[8];
    const float* b3    = (const float*)d_in[9];
    float* out = (float*)d_out;

    // workspace carve-up
    float* t      = (float*)d_ws;                      // N*64 floats
    float* agg    = t + (size_t)NN * 64;               // N*64 floats
    float* y      = agg + (size_t)NN * 64;             // N floats
    float* counts = y + NN;                            // G floats
    int*   cursor = (int*)(counts + GG);               // NBUK ints
    uint2* ep     = (uint2*)(cursor + NBUK + 1);       // NBUK*BCAP uint2 (8B-aligned)

    hipMemsetAsync(counts, 0, GG * sizeof(float), stream);
    hipMemsetAsync(cursor, 0, NBUK * sizeof(int), stream);
    hipMemsetAsync(out, 0, GG * sizeof(float), stream);

    k_counts<<<(NN + 255) / 256, 256, 0, stream>>>(batch, counts, NN);
    k_bin<<<NBINBLK, 256, 0, stream>>>(src, dst, ew, cursor, ep, EE);

    // layer 1: t = x @ W1 ; agg = bucketed aggregate(t)
    k_gemm64<false><<<(NN + 3) / 4, 256, 0, stream>>>(x, W1, nullptr, nullptr, nullptr, t, NN);
    k_agg<0><<<NBUK, 512, 0, stream>>>(t, ep, cursor, agg, nullptr, nullptr, nullptr, nullptr);

    // layer 2: t = sigmoid(agg/cpn + b1) @ W2 ; y = fused aggregate+sigmoid+dot(W3)
    k_gemm64<true><<<(NN + 3) / 4, 256, 0, stream>>>(agg, W2, b1, counts, batch, t, NN);
    k_agg<1><<<NBUK, 512, 0, stream>>>(t, ep, cursor, y, b2, W3, counts, batch);

    // layer 3 + pool
    k_y3pool<<<NBUK, 256, 0, stream>>>(y, ep, cursor, b3, counts, batch, out);
}

// Round 5
// 530.121 us; speedup vs baseline: 3.2804x; 3.2804x over previous
//
#include <hip/hip_runtime.h>
#include <math.h>

#define NN 100000
#define EE 1600000
#define GG 1000
#define SB 512                      // scan block (elements == threads)
#define NB1 ((NN + SB - 1) / SB)    // 196 scan blocks
#define NBUK 391                    // ceil(NN/256) buckets of 256 dst nodes
#define EPB 4096                    // edges per binning block
#define NBINBLK ((EE + EPB - 1) / EPB)   // 391

// ---- counts[g] += 1 per node ------------------------------------------------
__global__ void k_counts(const int* __restrict__ batch, float* __restrict__ counts, int n) {
    int i = blockIdx.x * blockDim.x + threadIdx.x;
    if (i < n) atomicAdd(&counts[batch[i]], 1.0f);
}

// ---- hist[dst[e]]++ ---------------------------------------------------------
__global__ void k_hist(const int* __restrict__ dst, int* __restrict__ hist, int E) {
    int e = blockIdx.x * blockDim.x + threadIdx.x;
    if (e < E) atomicAdd(&hist[dst[e]], 1);
}

// ---- per-block inclusive scan of hist -> incl (stored in rowptr), partials --
__global__ void k_scan1(const int* __restrict__ hist, int* __restrict__ incl,
                        int* __restrict__ partials, int n) {
    __shared__ int s[SB];
    int i = blockIdx.x * SB + threadIdx.x;
    int v = (i < n) ? hist[i] : 0;
    s[threadIdx.x] = v;
    __syncthreads();
    for (int off = 1; off < SB; off <<= 1) {
        int t = (threadIdx.x >= off) ? s[threadIdx.x - off] : 0;
        __syncthreads();
        s[threadIdx.x] += t;
        __syncthreads();
    }
    if (i < n) incl[i] = s[threadIdx.x];
    if (threadIdx.x == SB - 1) partials[blockIdx.x] = s[SB - 1];
}

// ---- single-block exclusive scan of partials (NB1 <= 256) ------------------
__global__ void k_scan2(int* __restrict__ partials, int nb) {
    __shared__ int s[256];
    int v = (threadIdx.x < nb) ? partials[threadIdx.x] : 0;
    s[threadIdx.x] = v;
    __syncthreads();
    for (int off = 1; off < 256; off <<= 1) {
        int t = (threadIdx.x >= off) ? s[threadIdx.x - off] : 0;
        __syncthreads();
        s[threadIdx.x] += t;
        __syncthreads();
    }
    if (threadIdx.x < nb) partials[threadIdx.x] = s[threadIdx.x] - v; // exclusive
}

// ---- rowptr[i] = exclusive prefix; rowptr[n] = E ---------------------------
__global__ void k_scan3(const int* __restrict__ hist, int* __restrict__ rowptr,
                        const int* __restrict__ partials, int n, int E) {
    int i = blockIdx.x * SB + threadIdx.x;
    if (i < n) rowptr[i] = rowptr[i] - hist[i] + partials[blockIdx.x];
    if (i == 0) rowptr[n] = E;
}

// ---- cursor[bk] = rowptr[bk*256]  (exact-packed bucket bases) ---------------
__global__ void k_seedcur(const int* __restrict__ rowptr, int* __restrict__ cursor) {
    int i = threadIdx.x + blockIdx.x * blockDim.x;
    if (i < NBUK) cursor[i] = rowptr[i * 256];
}

// ---- pass 1: bin edges by dst>>8 into exact-packed bucket ranges ------------
// record: x = (local_dst<<24) | src (src < 2^17), y = float bits of weight
__global__ void k_bin(const int* __restrict__ src, const int* __restrict__ dst,
                      const float* __restrict__ ew, int* __restrict__ cursor,
                      uint2* __restrict__ ep1, int E) {
    __shared__ int hist[NBUK];
    __shared__ int gbase[NBUK];
    int tid = threadIdx.x;
    for (int i = tid; i < NBUK; i += 256) hist[i] = 0;
    __syncthreads();

    int base = blockIdx.x * EPB;
    int b[16], rank[16];
    unsigned x[16], w[16];
#pragma unroll
    for (int u = 0; u < 16; u++) {
        int e = base + u * 256 + tid;
        if (e < E) {
            int d = dst[e];
            b[u] = d >> 8;
            x[u] = ((unsigned)(d & 255) << 24) | (unsigned)src[e];
            w[u] = __float_as_uint(ew[e]);
            rank[u] = atomicAdd(&hist[b[u]], 1);
        } else b[u] = -1;
    }
    __syncthreads();
    for (int i = tid; i < NBUK; i += 256) {
        int h = hist[i];
        gbase[i] = h ? atomicAdd(&cursor[i], h) : 0;
    }
    __syncthreads();
#pragma unroll
    for (int u = 0; u < 16; u++) {
        if (b[u] >= 0) ep1[gbase[b[u]] + rank[u]] = make_uint2(x[u], w[u]);
    }
}

// ---- pass 2: within-bucket scatter to per-dst CSR positions -----------------
// reads coalesced; writes confined to the bucket's ~32KB window (L2-local)
__global__ void k_bin2(const uint2* __restrict__ ep1, const int* __restrict__ rowptr,
                       uint2* __restrict__ ep2, int n) {
    __shared__ int cur[256];
    int tid = threadIdx.x;
    int bk = blockIdx.x;
    int node0 = bk * 256;
    int nvalid = n - node0; if (nvalid > 256) nvalid = 256;
    cur[tid] = (tid < nvalid) ? rowptr[node0 + tid] : 0;
    __syncthreads();
    int beg = rowptr[node0];
    int end = rowptr[node0 + nvalid];
    for (int p = beg + tid; p < end; p += 256) {
        uint2 r = ep1[p];
        int ld = (int)(r.x >> 24);
        int pos = atomicAdd(&cur[ld], 1);
        ep2[pos] = r;
    }
}

// ---- out[r][c] = sum_k in'[r][k] * W[k][c] ---------------------------------
// ACT: in'[r][k] = sigmoid(in[r][k]/cpn[r] + bPrev[k]); else in' = in.
template<bool ACT>
__global__ void k_gemm64(const float* __restrict__ in, const float* __restrict__ W,
                         const float* __restrict__ bPrev, const float* __restrict__ counts,
                         const int* __restrict__ batch, float* __restrict__ out, int n) {
    __shared__ float Ws[64 * 64];
    __shared__ float Rs[4][64];
    int tid = threadIdx.x;
    const float4* W4 = (const float4*)W;
    float4* Ws4 = (float4*)Ws;
#pragma unroll
    for (int i = 0; i < 4; i++) Ws4[tid + 256 * i] = W4[tid + 256 * i];

    int r = tid >> 6;
    int c = tid & 63;
    int row = blockIdx.x * 4 + r;
    float v = 0.f;
    if (row < n) {
        v = in[(size_t)row * 64 + c];
        if (ACT) {
            float cp = counts[batch[row]];
            v = v / cp + bPrev[c];
            v = 1.f / (1.f + __expf(-v));
        }
    }
    Rs[r][c] = v;
    __syncthreads();

    float acc = 0.f;
#pragma unroll
    for (int k = 0; k < 64; k++)
        acc = fmaf(Rs[r][k], Ws[k * 64 + c], acc);
    if (row < n) out[(size_t)row * 64 + c] = acc;
}

// ---- wave-per-node CSR gather, 4x MLP-unrolled; optional fused epilogue -----
// FUSE_Y=false: agg[node][lane] = sum_e w_e * t[src_e][lane]
// FUSE_Y=true:  y[node] = sum_lane sigmoid(acc/cpn + b2[lane]) * W3[lane]
template<bool FUSE_Y>
__global__ void k_gather64(const float* __restrict__ t, const int* __restrict__ rowptr,
                           const uint2* __restrict__ ep, float* __restrict__ outp,
                           const float* __restrict__ b2, const float* __restrict__ W3,
                           const float* __restrict__ counts, const int* __restrict__ batch,
                           int n) {
    int wid = (blockIdx.x * blockDim.x + threadIdx.x) >> 6;
    int lane = threadIdx.x & 63;
    wid = __builtin_amdgcn_readfirstlane(wid);   // wave-uniform -> scalar edge loads
    if (wid >= n) return;
    int beg = rowptr[wid], end = rowptr[wid + 1];
    float acc = 0.f;
    int e = beg;
    for (; e + 4 <= end; e += 4) {
        uint2 r0 = ep[e], r1 = ep[e + 1], r2 = ep[e + 2], r3 = ep[e + 3];
        float v0 = t[(size_t)(r0.x & 0xFFFFFFu) * 64 + lane];
        float v1 = t[(size_t)(r1.x & 0xFFFFFFu) * 64 + lane];
        float v2 = t[(size_t)(r2.x & 0xFFFFFFu) * 64 + lane];
        float v3 = t[(size_t)(r3.x & 0xFFFFFFu) * 64 + lane];
        acc = fmaf(__uint_as_float(r0.y), v0, acc);
        acc = fmaf(__uint_as_float(r1.y), v1, acc);
        acc = fmaf(__uint_as_float(r2.y), v2, acc);
        acc = fmaf(__uint_as_float(r3.y), v3, acc);
    }
    for (; e < end; e++) {
        uint2 r = ep[e];
        acc = fmaf(__uint_as_float(r.y), t[(size_t)(r.x & 0xFFFFFFu) * 64 + lane], acc);
    }
    if (!FUSE_Y) {
        outp[(size_t)wid * 64 + lane] = acc;
    } else {
        float cp = counts[batch[wid]];
        float v = acc / cp + b2[lane];
        v = 1.f / (1.f + __expf(-v));
        v *= W3[lane];
#pragma unroll
        for (int off = 32; off > 0; off >>= 1) v += __shfl_down(v, off, 64);
        if (lane == 0) outp[wid] = v;
    }
}

// ---- per-node layer-3 gather fused with graph-mean pool, 4x unrolled --------
__global__ void k_gather1_pool(const float* __restrict__ y, const int* __restrict__ rowptr,
                               const uint2* __restrict__ ep,
                               const float* __restrict__ b3, const float* __restrict__ counts,
                               const int* __restrict__ batch, float* __restrict__ out, int n) {
    int i = blockIdx.x * blockDim.x + threadIdx.x;
    if (i >= n) return;
    int beg = rowptr[i], end = rowptr[i + 1];
    float acc = 0.f;
    int e = beg;
    for (; e + 4 <= end; e += 4) {
        uint2 r0 = ep[e], r1 = ep[e + 1], r2 = ep[e + 2], r3 = ep[e + 3];
        float y0 = y[r0.x & 0xFFFFFFu], y1 = y[r1.x & 0xFFFFFFu];
        float y2 = y[r2.x & 0xFFFFFFu], y3 = y[r3.x & 0xFFFFFFu];
        acc = fmaf(__uint_as_float(r0.y), y0, acc);
        acc = fmaf(__uint_as_float(r1.y), y1, acc);
        acc = fmaf(__uint_as_float(r2.y), y2, acc);
        acc = fmaf(__uint_as_float(r3.y), y3, acc);
    }
    for (; e < end; e++) {
        uint2 r = ep[e];
        acc = fmaf(__uint_as_float(r.y), y[r.x & 0xFFFFFFu], acc);
    }
    int b = batch[i];
    float c = counts[b];
    atomicAdd(&out[b], (acc / c + b3[0]) / c);
}

extern "C" void kernel_launch(void* const* d_in, const int* in_sizes, int n_in,
                              void* d_out, int out_size, void* d_ws, size_t ws_size,
                              hipStream_t stream) {
    const float* x     = (const float*)d_in[0];
    const int*   ei    = (const int*)d_in[1];
    const int*   src   = ei;
    const int*   dst   = ei + EE;
    const float* ew    = (const float*)d_in[2];
    const int*   batch = (const int*)d_in[3];
    const float* W1    = (const float*)d_in[4];
    const float* b1    = (const float*)d_in[5];
    const float* W2    = (const float*)d_in[6];
    const float* b2    = (const float*)d_in[7];
    const float* W3    = (const float*)d_in[8];
    const float* b3    = (const float*)d_in[9];
    float* out = (float*)d_out;

    // workspace carve-up
    float* t      = (float*)d_ws;                      // N*64 floats
    float* agg    = t + (size_t)NN * 64;               // N*64 floats (also aliases ep1)
    float* y      = agg + (size_t)NN * 64;             // N floats
    float* counts = y + NN;                            // G floats
    uint2* ep2    = (uint2*)(counts + GG);             // E uint2 (final CSR records)
    int*   hist   = (int*)(ep2 + EE);                  // N ints
    int*   rowptr = hist + NN;                         // N+1 ints
    int*   cursor = rowptr + NN + 1;                   // NBUK ints
    int*   partials = cursor + NBUK;                   // NB1 ints
    uint2* ep1    = (uint2*)agg;                       // E uint2, dead before first gather

    hipMemsetAsync(counts, 0, GG * sizeof(float), stream);
    hipMemsetAsync(hist, 0, NN * sizeof(int), stream);
    hipMemsetAsync(out, 0, GG * sizeof(float), stream);

    // counts + CSR build (hist -> rowptr -> bucket bin -> within-bucket scatter)
    k_counts<<<(NN + 255) / 256, 256, 0, stream>>>(batch, counts, NN);
    k_hist<<<(EE + 255) / 256, 256, 0, stream>>>(dst, hist, EE);
    k_scan1<<<NB1, SB, 0, stream>>>(hist, rowptr, partials, NN);
    k_scan2<<<1, 256, 0, stream>>>(partials, NB1);
    k_scan3<<<NB1, SB, 0, stream>>>(hist, rowptr, partials, NN, EE);
    k_seedcur<<<(NBUK + 255) / 256, 256, 0, stream>>>(rowptr, cursor);
    k_bin<<<NBINBLK, 256, 0, stream>>>(src, dst, ew, cursor, ep1, EE);
    k_bin2<<<NBUK, 256, 0, stream>>>(ep1, rowptr, ep2, NN);

    // layer 1: t = x @ W1 ; agg = gather(t)   (ep1 is dead from here on)
    k_gemm64<false><<<(NN + 3) / 4, 256, 0, stream>>>(x, W1, nullptr, nullptr, nullptr, t, NN);
    k_gather64<false><<<((size_t)NN * 64 + 255) / 256, 256, 0, stream>>>(
        t, rowptr, ep2, agg, nullptr, nullptr, nullptr, nullptr, NN);

    // layer 2: t = sigmoid(agg/cpn + b1) @ W2 ; y = fused gather+sigmoid+dot(W3)
    k_gemm64<true><<<(NN + 3) / 4, 256, 0, stream>>>(agg, W2, b1, counts, batch, t, NN);
    k_gather64<true><<<((size_t)NN * 64 + 255) / 256, 256, 0, stream>>>(
        t, rowptr, ep2, y, b2, W3, counts, batch, NN);

    // layer 3 + pool
    k_gather1_pool<<<(NN + 255) / 256, 256, 0, stream>>>(y, rowptr, ep2, b3, counts, batch, out, NN);
}

// Round 6
// 461.267 us; speedup vs baseline: 3.7700x; 1.1493x over previous
//
#include <hip/hip_runtime.h>
#include <math.h>

#define NN 100000
#define EE 1600000
#define GG 1000
#define NBUK 391                    // ceil(NN/256) buckets of 256 dst nodes
#define BCAP 4608                   // bucket capacity: mean 4092, +8 sigma
#define EPB 4096                    // edges per binning block
#define NBINBLK ((EE + EPB - 1) / EPB)   // 391

// ---- counts[g] += 1 per node ------------------------------------------------
__global__ void k_counts(const int* __restrict__ batch, float* __restrict__ counts, int n) {
    int i = blockIdx.x * blockDim.x + threadIdx.x;
    if (i < n) atomicAdd(&counts[batch[i]], 1.0f);
}

// ---- pass 1: bin edges by dst>>8 into fixed-capacity bucket arrays ----------
// record: x = (local_dst<<24) | src (src < 2^17), y = float bits of weight
__global__ void k_bin(const int* __restrict__ src, const int* __restrict__ dst,
                      const float* __restrict__ ew, int* __restrict__ bukcnt,
                      uint2* __restrict__ ep1, int E) {
    __shared__ int hist[NBUK];
    __shared__ int gbase[NBUK];
    int tid = threadIdx.x;
    for (int i = tid; i < NBUK; i += 256) hist[i] = 0;
    __syncthreads();

    int base = blockIdx.x * EPB;
    int b[16], rank[16];
    unsigned x[16], w[16];
#pragma unroll
    for (int u = 0; u < 16; u++) {
        int e = base + u * 256 + tid;
        if (e < E) {
            int d = dst[e];
            b[u] = d >> 8;
            x[u] = ((unsigned)(d & 255) << 24) | (unsigned)src[e];
            w[u] = __float_as_uint(ew[e]);
            rank[u] = atomicAdd(&hist[b[u]], 1);
        } else b[u] = -1;
    }
    __syncthreads();
    for (int i = tid; i < NBUK; i += 256) {
        int h = hist[i];
        gbase[i] = h ? atomicAdd(&bukcnt[i], h) : 0;
    }
    __syncthreads();
#pragma unroll
    for (int u = 0; u < 16; u++) {
        if (b[u] >= 0) ep1[(size_t)b[u] * BCAP + gbase[b[u]] + rank[u]] = make_uint2(x[u], w[u]);
    }
}

// ---- exclusive scan of bucket counts -> bukbase; rowptr[NN] = E -------------
__global__ void k_bukscan(const int* __restrict__ bukcnt, int* __restrict__ bukbase,
                          int* __restrict__ rowptr) {
    __shared__ int s[512];
    int tid = threadIdx.x;
    int v = (tid < NBUK) ? bukcnt[tid] : 0;
    s[tid] = v;
    __syncthreads();
    for (int off = 1; off < 512; off <<= 1) {
        int t = (tid >= off) ? s[tid - off] : 0;
        __syncthreads();
        s[tid] += t;
        __syncthreads();
    }
    if (tid < NBUK) bukbase[tid] = s[tid] - v;   // exclusive
    if (tid == 0) { bukbase[NBUK] = EE; rowptr[NN] = EE; }
}

// ---- pass 2: per-bucket LDS hist + scan -> rowptr; scatter to CSR -----------
// all reads/writes confined to the bucket's ~36KB window (L2-local)
__global__ void k_bin2(const uint2* __restrict__ ep1, const int* __restrict__ bukcnt,
                       const int* __restrict__ bukbase, uint2* __restrict__ ep2,
                       int* __restrict__ rowptr, int n) {
    __shared__ int h[256];
    __shared__ int s[256];
    __shared__ int cur[256];
    int tid = threadIdx.x;
    int bk = blockIdx.x;
    h[tid] = 0;
    __syncthreads();
    int cnt = bukcnt[bk];
    size_t ebase = (size_t)bk * BCAP;
    for (int e = tid; e < cnt; e += 256)
        atomicAdd(&h[ep1[ebase + e].x >> 24], 1);
    __syncthreads();
    s[tid] = h[tid];
    __syncthreads();
    for (int off = 1; off < 256; off <<= 1) {
        int t = (tid >= off) ? s[tid - off] : 0;
        __syncthreads();
        s[tid] += t;
        __syncthreads();
    }
    int base = bukbase[bk];
    int pfx = base + s[tid] - h[tid];            // global exclusive prefix for this dst
    int node = bk * 256 + tid;
    if (node < n) rowptr[node] = pfx;
    cur[tid] = pfx;
    __syncthreads();
    for (int e = tid; e < cnt; e += 256) {
        uint2 r = ep1[ebase + e];
        int pos = atomicAdd(&cur[r.x >> 24], 1);
        ep2[pos] = r;
    }
}

// ---- out[r][c] = sum_k in'[r][k] * W[k][c] ---------------------------------
// ACT: in'[r][k] = sigmoid(in[r][k]/cpn[r] + bPrev[k]); else in' = in.
template<bool ACT>
__global__ void k_gemm64(const float* __restrict__ in, const float* __restrict__ W,
                         const float* __restrict__ bPrev, const float* __restrict__ counts,
                         const int* __restrict__ batch, float* __restrict__ out, int n) {
    __shared__ float Ws[64 * 64];
    __shared__ float Rs[4][64];
    int tid = threadIdx.x;
    const float4* W4 = (const float4*)W;
    float4* Ws4 = (float4*)Ws;
#pragma unroll
    for (int i = 0; i < 4; i++) Ws4[tid + 256 * i] = W4[tid + 256 * i];

    int r = tid >> 6;
    int c = tid & 63;
    int row = blockIdx.x * 4 + r;
    float v = 0.f;
    if (row < n) {
        v = in[(size_t)row * 64 + c];
        if (ACT) {
            float cp = counts[batch[row]];
            v = v / cp + bPrev[c];
            v = 1.f / (1.f + __expf(-v));
        }
    }
    Rs[r][c] = v;
    __syncthreads();

    float acc = 0.f;
#pragma unroll
    for (int k = 0; k < 64; k++)
        acc = fmaf(Rs[r][k], Ws[k * 64 + c], acc);
    if (row < n) out[(size_t)row * 64 + c] = acc;
}

// ---- wave-per-node CSR gather, 8x MLP-unrolled; optional fused epilogue -----
// FUSE_Y=false: agg[node][lane] = sum_e w_e * t[src_e][lane]
// FUSE_Y=true:  y[node] = sum_lane sigmoid(acc/cpn + b2[lane]) * W3[lane]
template<bool FUSE_Y>
__global__ void k_gather64(const float* __restrict__ t, const int* __restrict__ rowptr,
                           const uint2* __restrict__ ep, float* __restrict__ outp,
                           const float* __restrict__ b2, const float* __restrict__ W3,
                           const float* __restrict__ counts, const int* __restrict__ batch,
                           int n) {
    int wid = (blockIdx.x * blockDim.x + threadIdx.x) >> 6;
    int lane = threadIdx.x & 63;
    wid = __builtin_amdgcn_readfirstlane(wid);   // wave-uniform -> scalar edge loads
    if (wid >= n) return;
    int beg = rowptr[wid], end = rowptr[wid + 1];
    float acc = 0.f;
    int e = beg;
    for (; e + 8 <= end; e += 8) {
        uint2 r[8];
#pragma unroll
        for (int u = 0; u < 8; u++) r[u] = ep[e + u];
        float v[8];
#pragma unroll
        for (int u = 0; u < 8; u++) v[u] = t[(size_t)(r[u].x & 0xFFFFFFu) * 64 + lane];
#pragma unroll
        for (int u = 0; u < 8; u++) acc = fmaf(__uint_as_float(r[u].y), v[u], acc);
    }
    for (; e < end; e++) {
        uint2 r = ep[e];
        acc = fmaf(__uint_as_float(r.y), t[(size_t)(r.x & 0xFFFFFFu) * 64 + lane], acc);
    }
    if (!FUSE_Y) {
        outp[(size_t)wid * 64 + lane] = acc;
    } else {
        float cp = counts[batch[wid]];
        float v = acc / cp + b2[lane];
        v = 1.f / (1.f + __expf(-v));
        v *= W3[lane];
#pragma unroll
        for (int off = 32; off > 0; off >>= 1) v += __shfl_down(v, off, 64);
        if (lane == 0) outp[wid] = v;
    }
}

// ---- per-node layer-3 gather fused with graph-mean pool, 4x unrolled --------
__global__ void k_gather1_pool(const float* __restrict__ y, const int* __restrict__ rowptr,
                               const uint2* __restrict__ ep,
                               const float* __restrict__ b3, const float* __restrict__ counts,
                               const int* __restrict__ batch, float* __restrict__ out, int n) {
    int i = blockIdx.x * blockDim.x + threadIdx.x;
    if (i >= n) return;
    int beg = rowptr[i], end = rowptr[i + 1];
    float acc = 0.f;
    int e = beg;
    for (; e + 4 <= end; e += 4) {
        uint2 r0 = ep[e], r1 = ep[e + 1], r2 = ep[e + 2], r3 = ep[e + 3];
        float y0 = y[r0.x & 0xFFFFFFu], y1 = y[r1.x & 0xFFFFFFu];
        float y2 = y[r2.x & 0xFFFFFFu], y3 = y[r3.x & 0xFFFFFFu];
        acc = fmaf(__uint_as_float(r0.y), y0, acc);
        acc = fmaf(__uint_as_float(r1.y), y1, acc);
        acc = fmaf(__uint_as_float(r2.y), y2, acc);
        acc = fmaf(__uint_as_float(r3.y), y3, acc);
    }
    for (; e < end; e++) {
        uint2 r = ep[e];
        acc = fmaf(__uint_as_float(r.y), y[r.x & 0xFFFFFFu], acc);
    }
    int b = batch[i];
    float c = counts[b];
    atomicAdd(&out[b], (acc / c + b3[0]) / c);
}

extern "C" void kernel_launch(void* const* d_in, const int* in_sizes, int n_in,
                              void* d_out, int out_size, void* d_ws, size_t ws_size,
                              hipStream_t stream) {
    const float* x     = (const float*)d_in[0];
    const int*   ei    = (const int*)d_in[1];
    const int*   src   = ei;
    const int*   dst   = ei + EE;
    const float* ew    = (const float*)d_in[2];
    const int*   batch = (const int*)d_in[3];
    const float* W1    = (const float*)d_in[4];
    const float* b1    = (const float*)d_in[5];
    const float* W2    = (const float*)d_in[6];
    const float* b2    = (const float*)d_in[7];
    const float* W3    = (const float*)d_in[8];
    const float* b3    = (const float*)d_in[9];
    float* out = (float*)d_out;

    // workspace carve-up
    float* t      = (float*)d_ws;                      // N*64 floats
    float* agg    = t + (size_t)NN * 64;               // N*64 floats (aliases ep1)
    float* y      = agg + (size_t)NN * 64;             // N floats
    float* counts = y + NN;                            // G floats
    uint2* ep2    = (uint2*)(counts + GG);             // E uint2 (final CSR records)
    int*   bukcnt = (int*)(ep2 + EE);                  // NBUK ints
    int*   bukbase= bukcnt + NBUK;                     // NBUK+1 ints
    int*   rowptr = bukbase + NBUK + 1;                // NN+1 ints
    uint2* ep1    = (uint2*)agg;                       // NBUK*BCAP uint2 (14.4 MB < 25.6 MB)

    hipMemsetAsync(counts, 0, GG * sizeof(float), stream);
    hipMemsetAsync(bukcnt, 0, NBUK * sizeof(int), stream);
    hipMemsetAsync(out, 0, GG * sizeof(float), stream);

    // counts + bucket-local CSR build (no global-atomic histogram, no global scans)
    k_counts<<<(NN + 255) / 256, 256, 0, stream>>>(batch, counts, NN);
    k_bin<<<NBINBLK, 256, 0, stream>>>(src, dst, ew, bukcnt, ep1, EE);
    k_bukscan<<<1, 512, 0, stream>>>(bukcnt, bukbase, rowptr);
    k_bin2<<<NBUK, 256, 0, stream>>>(ep1, bukcnt, bukbase, ep2, rowptr, NN);

    // layer 1: t = x @ W1 ; agg = gather(t)   (ep1 dead from here on)
    k_gemm64<false><<<(NN + 3) / 4, 256, 0, stream>>>(x, W1, nullptr, nullptr, nullptr, t, NN);
    k_gather64<false><<<((size_t)NN * 64 + 255) / 256, 256, 0, stream>>>(
        t, rowptr, ep2, agg, nullptr, nullptr, nullptr, nullptr, NN);

    // layer 2: t = sigmoid(agg/cpn + b1) @ W2 ; y = fused gather+sigmoid+dot(W3)
    k_gemm64<true><<<(NN + 3) / 4, 256, 0, stream>>>(agg, W2, b1, counts, batch, t, NN);
    k_gather64<true><<<((size_t)NN * 64 + 255) / 256, 256, 0, stream>>>(
        t, rowptr, ep2, y, b2, W3, counts, batch, NN);

    // layer 3 + pool
    k_gather1_pool<<<(NN + 255) / 256, 256, 0, stream>>>(y, rowptr, ep2, b3, counts, batch, out, NN);
}